// Round 6
// baseline (198.368 us; speedup 1.0000x reference)
//
#include <hip/hip_runtime.h>

#define N_NODES 16384
#define F_IN    128
#define F_HID   256
#define F_OUT   128
#define LN_EPS  1e-5f
#define CAP     128   // ELL slots/row; P(deg>128) ~ 1e-20 for Poisson(32)
#define H0STR   136   // LDS h0 stride (ushorts)
#define H1STR   264   // LDS post-LN stride (ushorts)
#define REPSTR  132   // LDS C2 repack stride (ushorts)

typedef __attribute__((ext_vector_type(8))) short bf16x8;
typedef __attribute__((ext_vector_type(4))) float f32x4;
typedef unsigned long long u64;

__device__ __forceinline__ unsigned short bf16rne(float f) {
    unsigned u = __float_as_uint(f);
    unsigned r = (u + 0x7fffu + ((u >> 16) & 1u)) >> 16;   // round-to-nearest-even
    return (unsigned short)r;
}
__device__ __forceinline__ float bf_lo(unsigned v) { return __uint_as_float(v << 16); }
__device__ __forceinline__ float bf_hi(unsigned v) { return __uint_as_float(v & 0xffff0000u); }

// ---------------------------------------------------------------------------
// Tiny prologue: zero cur (blocks 0..63) + detect int64 vs int32 edge_index
// (block 64: odd u32 words all zero => int64).
__global__ void pre_small_kernel(int* __restrict__ cur, const unsigned* __restrict__ ei,
                                 int* __restrict__ mode) {
    int b = blockIdx.x, t = threadIdx.x;
    if (b < 64) {
        cur[b * 256 + t] = 0;
    } else {
        __shared__ int nz;
        if (t == 0) nz = 0;
        __syncthreads();
        for (int it = 0; it < 4; ++it) {
            int idx = 2 * (t + it * 256) + 1;
            if (ei[idx] != 0u) nz = 1;        // benign race
        }
        __syncthreads();
        if (t == 0) *mode = (nz == 0) ? 1 : 0;  // 1 => int64
    }
}

// ---------------------------------------------------------------------------
// Fused prep: ELL fill + x fp32->bf16 + W1/W2 transpose-to-bf16, one grid so
// the streaming conversions overlap fill's atomic latency.
__global__ void prep_fill_kernel(const void* __restrict__ ei, const int* __restrict__ mode,
                                 int* __restrict__ cur, int2* __restrict__ ed, int E, int nF,
                                 const float* __restrict__ x, unsigned short* __restrict__ xb,
                                 const float* __restrict__ W1, unsigned short* __restrict__ W1t,
                                 const float* __restrict__ W2, unsigned short* __restrict__ W2t) {
    int b = blockIdx.x, t = threadIdx.x;
    if (b < nF) {
        int base = b * 1024 + t;
        int m = *mode;
#pragma unroll
        for (int u = 0; u < 4; ++u) {
            int e = base + u * 256;
            if (e >= E) continue;
            int r, c;
            if (m) {
                const long long* p = (const long long*)ei;
                r = (int)p[e]; c = (int)p[e + E];
            } else {
                const int* p = (const int*)ei;
                r = p[e]; c = p[e + E];
            }
            if (((unsigned)r | (unsigned)c) >= N_NODES) continue;   // replay-safety guard
            int pos = atomicAdd(&cur[r], 1);
            if (pos < CAP) ed[r * CAP + pos] = make_int2(c, e);
        }
    } else if (b < nF + 2048) {
        int i = ((b - nF) * 256 + t) * 4;
        float4 v = *(const float4*)&x[i];
        ushort4 o;
        o.x = bf16rne(v.x); o.y = bf16rne(v.y); o.z = bf16rne(v.z); o.w = bf16rne(v.w);
        *(ushort4*)&xb[i] = o;
    } else if (b < nF + 2176) {
        int id = (b - nF - 2048) * 256 + t;   // [0, 32768)
        int n = id >> 7, k = id & 127;
        W1t[id] = bf16rne(W1[(size_t)k * F_HID + n]);
    } else {
        int id = (b - nF - 2176) * 256 + t;   // [0, 32768)
        int n = id >> 8, k = id & 255;
        W2t[id] = bf16rne(W2[(size_t)k * F_OUT + n]);
    }
}

// ---------------------------------------------------------------------------
// Fused sort + dedupe + SpMM1 + MLP. 16 rows/block, 16 waves (1024 thr),
// 1 row/wave. Each wave bitonic-sorts its row's {col,eid} list by packed u64
// key in LDS (fixed 128-slot sort, 28 stages). Sorted order gives:
//  1) O(d) dedupe: entry live iff next entry has different col (sort is
//     (col,eid) ascending, so last of a col-group = max eid = last-edge-wins;
//     kill rule identical to the O(d^2) version, bit-identical results).
//  2) Ascending-column gathers: all resident waves sweep the same narrow
//     column window together -> xb slice stays L2-resident (round-5 counters:
//     75 MB FETCH ~ 50% gather miss from random-order sweeps).
//  3) ed written back sorted -> spmm2 inherits the same locality free.
__launch_bounds__(1024, 8)
__global__ void agg_mlp_kernel(const float* __restrict__ ew, int* __restrict__ cur,
                               int2* __restrict__ ed, float* __restrict__ invdeg,
                               const unsigned* __restrict__ xb,
                               const unsigned short* __restrict__ W1t,
                               const unsigned short* __restrict__ W2t,
                               const float* __restrict__ b1,
                               const float* __restrict__ ln_g, const float* __restrict__ ln_b,
                               unsigned short* __restrict__ h2b) {
    __shared__ u64   skey[16][CAP];             // 16 KB (sort keys)
    __shared__ int   scol[16][CAP];             // 8 KB
    __shared__ float sw[16][CAP];               // 8 KB
    __shared__ unsigned short H0[16 * H0STR];   // 4.25 KB; reused as C2 repack
    __shared__ unsigned short H1[16 * H1STR];   // 8.25 KB
    __shared__ float red[2][16][16];            // 2 KB  (LN partial {s,q}[wave][row])

    int t = threadIdx.x, wave = t >> 6, lane = t & 63;
    int lnid = lane & 15, quad = lane >> 4;
    int half = lane >> 5, hl = lane & 31;
    int Rbase = blockIdx.x * 16;
    int r = Rbase + wave;

    // ---- stage packed keys (col<<32 | eid) into wave-private LDS ----
    int d = cur[r];
    if (d > CAP) d = CAP;
    int2* row = ed + (size_t)r * CAP;
    for (int i = lane; i < d; i += 64) {
        int2 e = row[i];
        skey[wave][i] = ((u64)(unsigned)e.x << 32) | (unsigned)e.y;
    }
    for (int i = d + lane; i < CAP; i += 64)
        skey[wave][i] = ~0ull;                    // padding sorts to the end
    asm volatile("s_waitcnt lgkmcnt(0)" ::: "memory");   // wave-local LDS ordering

    // ---- bitonic sort, 128 elements, 64 lanes (one compare-exchange/lane) ----
    u64* K = skey[wave];
#pragma unroll 1
    for (int k = 2; k <= CAP; k <<= 1) {
#pragma unroll 1
        for (int j = k >> 1; j > 0; j >>= 1) {
            int i = ((lane & ~(j - 1)) << 1) | (lane & (j - 1));  // bit-j-clear elems
            int l = i | j;
            u64 a = K[i], b = K[l];
            bool up = ((i & k) == 0);
            if ((a > b) == up) { K[i] = b; K[l] = a; }
            asm volatile("s_waitcnt lgkmcnt(0)" ::: "memory");
        }
    }

    // ---- O(d) dedupe on sorted list + weight gather + writeback ----
    float wsum = 0.0f;
    for (int i = lane; i < d; i += 64) {
        u64 key = skey[wave][i];
        int c = (int)(key >> 32);
        int eid = (int)(key & 0xffffffffu);
        bool live = (i == CAP - 1) || ((int)(skey[wave][i + 1] >> 32) != c);
        float w = live ? ew[eid] : 0.0f;
        scol[wave][i] = c;
        sw[wave][i] = w;
        row[i] = make_int2(c, __float_as_int(w));   // sorted writeback for spmm2
        wsum += w;
    }
    asm volatile("s_waitcnt lgkmcnt(0)" ::: "memory");
    for (int off = 32; off; off >>= 1) wsum += __shfl_xor(wsum, off, 64);
    float inv = 1.0f / (1.0f + wsum);                // +1 self-loop; >=1 so clip no-op
    if (lane == 0) { invdeg[r] = inv; cur[r] = d; }

    // ---- half-wave uint2 gather-SpMM (ascending cols): f = 4*hl + k ----
    const uint2* xb2 = (const uint2*)xb;
    uint2 sv = xb2[(size_t)r * 32 + hl];
    float selfw = half ? 0.0f : 1.0f;
    float a0 = selfw * bf_lo(sv.x), a1 = selfw * bf_hi(sv.x);
    float a2 = selfw * bf_lo(sv.y), a3 = selfw * bf_hi(sv.y);
    int j = 0;
    for (; j + 16 <= d; j += 16) {
        int c[8]; float w[8]; uint2 v[8];
#pragma unroll
        for (int u = 0; u < 8; ++u) {
            c[u] = scol[wave][j + 2 * u + half];
            w[u] = sw[wave][j + 2 * u + half];
        }
#pragma unroll
        for (int u = 0; u < 8; ++u) v[u] = xb2[(size_t)c[u] * 32 + hl];
#pragma unroll
        for (int u = 0; u < 8; ++u) {
            a0 += w[u] * bf_lo(v[u].x); a1 += w[u] * bf_hi(v[u].x);
            a2 += w[u] * bf_lo(v[u].y); a3 += w[u] * bf_hi(v[u].y);
        }
    }
    for (; j + 2 <= d; j += 2) {
        int cc = scol[wave][j + half];
        float w = sw[wave][j + half];
        uint2 v = xb2[(size_t)cc * 32 + hl];
        a0 += w * bf_lo(v.x); a1 += w * bf_hi(v.x);
        a2 += w * bf_lo(v.y); a3 += w * bf_hi(v.y);
    }
    if (j < d) {                                      // odd tail: half 0 only
        int cc = scol[wave][j];
        float w = half ? 0.0f : sw[wave][j];
        uint2 v = xb2[(size_t)cc * 32 + hl];
        a0 += w * bf_lo(v.x); a1 += w * bf_hi(v.x);
        a2 += w * bf_lo(v.y); a3 += w * bf_hi(v.y);
    }
    a0 += __shfl_xor(a0, 32, 64); a1 += __shfl_xor(a1, 32, 64);
    a2 += __shfl_xor(a2, 32, 64); a3 += __shfl_xor(a3, 32, 64);
    if (half == 0) {
        unsigned w0 = ((unsigned)bf16rne(a1 * inv) << 16) | (unsigned)bf16rne(a0 * inv);
        unsigned w1 = ((unsigned)bf16rne(a3 * inv) << 16) | (unsigned)bf16rne(a2 * inv);
        *(uint2*)&H0[wave * H0STR + hl * 4] = make_uint2(w0, w1);   // 8B aligned
    }
    __syncthreads();   // all 16 h0 rows staged

    // ---- stage A: C1[16x256] = h0 @ W1, K=128; wave handles ct = wave ----
    bf16x8 a[4];
#pragma unroll
    for (int ch = 0; ch < 4; ++ch)
        a[ch] = *(const bf16x8*)&H0[lnid * H0STR + ch * 32 + quad * 8];
    f32x4 acc = {0.0f, 0.0f, 0.0f, 0.0f};
    {
        const unsigned short* wrow = &W1t[(size_t)(wave * 16 + lnid) * F_IN];
#pragma unroll
        for (int ch = 0; ch < 4; ++ch) {
            bf16x8 b = *(const bf16x8*)&wrow[ch * 32 + quad * 8];
            acc = __builtin_amdgcn_mfma_f32_16x16x32_bf16(a[ch], b, acc, 0, 0, 0);
        }
    }
    // bias + LN partial stats (rows in (quad,reg); this wave's 16 cols in lnid)
    float s[4], q[4];
    {
        float bv = b1[wave * 16 + lnid];
#pragma unroll
        for (int rr = 0; rr < 4; ++rr) {
            float v = acc[rr] + bv;
            acc[rr] = v;
            s[rr] = v; q[rr] = v * v;
        }
    }
#pragma unroll
    for (int rr = 0; rr < 4; ++rr)
        for (int off = 1; off < 16; off <<= 1) {
            s[rr] += __shfl_xor(s[rr], off, 64);
            q[rr] += __shfl_xor(q[rr], off, 64);
        }
    if (lnid == 0) {
#pragma unroll
        for (int rr = 0; rr < 4; ++rr) {
            red[0][wave][quad * 4 + rr] = s[rr];
            red[1][wave][quad * 4 + rr] = q[rr];
        }
    }
    __syncthreads();
    float mean[4], rinv[4];
#pragma unroll
    for (int rr = 0; rr < 4; ++rr) {
        int rowi = quad * 4 + rr;
        float S = 0.0f, Q = 0.0f;
#pragma unroll
        for (int w2 = 0; w2 < 16; ++w2) { S += red[0][w2][rowi]; Q += red[1][w2][rowi]; }
        mean[rr] = S * (1.0f / F_HID);
        float var = Q * (1.0f / F_HID) - mean[rr] * mean[rr];
        rinv[rr] = rsqrtf(var + LN_EPS);
    }
    {
        int c = wave * 16 + lnid;
        float g = ln_g[c], bb = ln_b[c];
#pragma unroll
        for (int rr = 0; rr < 4; ++rr) {
            float v = fmaxf((acc[rr] - mean[rr]) * rinv[rr] * g + bb, 0.0f);
            H1[(quad * 4 + rr) * H1STR + c] = bf16rne(v);
        }
    }
    __syncthreads();   // H1 complete; H0 a-frags long consumed -> reusable

    // ---- stage B: C2[16x128] = H1 @ W2, K=256; waves 0-7, ct = wave ----
    unsigned short* rep = H0;   // repack area (16 x REPSTR fits in 16 x H0STR)
    if (wave < 8) {
        bf16x8 a2[8];
#pragma unroll
        for (int ch = 0; ch < 8; ++ch)
            a2[ch] = *(const bf16x8*)&H1[lnid * H1STR + ch * 32 + quad * 8];
        f32x4 c2 = {0.0f, 0.0f, 0.0f, 0.0f};
        const unsigned short* wrow = &W2t[(size_t)(wave * 16 + lnid) * F_HID];
#pragma unroll
        for (int ch = 0; ch < 8; ++ch) {
            bf16x8 b = *(const bf16x8*)&wrow[ch * 32 + quad * 8];
            c2 = __builtin_amdgcn_mfma_f32_16x16x32_bf16(a2[ch], b, c2, 0, 0, 0);
        }
#pragma unroll
        for (int rr = 0; rr < 4; ++rr)
            rep[(quad * 4 + rr) * REPSTR + wave * 16 + lnid] = bf16rne(c2[rr]);
    }
    __syncthreads();   // drain before coalesced readback

    // coalesced store: 16 rows x 128 bf16 (512 ushort4, threads 0..511)
    if (t < 512) {
        int m = t >> 5, cg = t & 31;
        *(ushort4*)&h2b[(size_t)(Rbase + m) * F_OUT + cg * 4] =
            *(const ushort4*)&rep[m * REPSTR + cg * 4];
    }
}

// ---------------------------------------------------------------------------
// Gather SpMM (ELL, deduped weights in ed.y, SORTED cols): one wave per row,
// half-wave uint2 gathers. Ascending-column sweep -> L2-resident window.
__global__ void spmm2_kernel(const unsigned* __restrict__ xb, const int* __restrict__ cur,
                             const int2* __restrict__ ed, const float* __restrict__ invdeg,
                             const float* __restrict__ bias, float* __restrict__ outp) {
    int wave = threadIdx.x >> 6, lane = threadIdx.x & 63;
    int half = lane >> 5, hl = lane & 31;
    int r = blockIdx.x * 4 + wave;
    const int2* row = ed + (size_t)r * CAP;
    const uint2* xb2 = (const uint2*)xb;
    int d = cur[r];
    if (d > CAP) d = CAP;
    uint2 sv = xb2[(size_t)r * 32 + hl];
    float selfw = half ? 0.0f : 1.0f;
    float a0 = selfw * bf_lo(sv.x), a1 = selfw * bf_hi(sv.x);
    float a2 = selfw * bf_lo(sv.y), a3 = selfw * bf_hi(sv.y);
    int j = 0;
    for (; j + 16 <= d; j += 16) {
        int2 q[8]; uint2 v[8];
#pragma unroll
        for (int u = 0; u < 8; ++u) q[u] = row[j + 2 * u + half];
#pragma unroll
        for (int u = 0; u < 8; ++u) v[u] = xb2[(size_t)q[u].x * 32 + hl];
#pragma unroll
        for (int u = 0; u < 8; ++u) {
            float w = __int_as_float(q[u].y);
            a0 += w * bf_lo(v[u].x); a1 += w * bf_hi(v[u].x);
            a2 += w * bf_lo(v[u].y); a3 += w * bf_hi(v[u].y);
        }
    }
    for (; j + 2 <= d; j += 2) {
        int2 q = row[j + half];
        uint2 v = xb2[(size_t)q.x * 32 + hl];
        float w = __int_as_float(q.y);
        a0 += w * bf_lo(v.x); a1 += w * bf_hi(v.x);
        a2 += w * bf_lo(v.y); a3 += w * bf_hi(v.y);
    }
    if (j < d) {                                      // odd tail: half 0 only
        int2 q = row[j];
        float w = half ? 0.0f : __int_as_float(q.y);
        uint2 v = xb2[(size_t)q.x * 32 + hl];
        a0 += w * bf_lo(v.x); a1 += w * bf_hi(v.x);
        a2 += w * bf_lo(v.y); a3 += w * bf_hi(v.y);
    }
    a0 += __shfl_xor(a0, 32, 64); a1 += __shfl_xor(a1, 32, 64);
    a2 += __shfl_xor(a2, 32, 64); a3 += __shfl_xor(a3, 32, 64);
    if (half == 0) {
        float inv = invdeg[r];
        float4 o;
        o.x = a0 * inv + bias[4 * hl];     o.y = a1 * inv + bias[4 * hl + 1];
        o.z = a2 * inv + bias[4 * hl + 2]; o.w = a3 * inv + bias[4 * hl + 3];
        ((float4*)outp)[(size_t)r * 32 + hl] = o;
    }
}

// ---------------------------------------------------------------------------
extern "C" void kernel_launch(void* const* d_in, const int* in_sizes, int n_in,
                              void* d_out, int out_size, void* d_ws, size_t ws_size,
                              hipStream_t stream) {
    const float* x   = (const float*)d_in[0];
    const void*  ei  = d_in[1];
    const float* ew  = (const float*)d_in[2];
    const float* W1  = (const float*)d_in[3];
    const float* b1  = (const float*)d_in[4];
    const float* W2  = (const float*)d_in[5];
    const float* b2  = (const float*)d_in[6];
    const float* lng = (const float*)d_in[7];
    const float* lnb = (const float*)d_in[8];
    float* out = (float*)d_out;
    int E = in_sizes[2];

    char* w = (char*)d_ws;
    size_t off = 0;
    auto take = [&](size_t bytes) -> char* {
        char* p = w + off;
        off += (bytes + 255) & ~(size_t)255;
        return p;
    };
    int*   cur    = (int*)take((size_t)N_NODES * 4);
    float* invdeg = (float*)take((size_t)N_NODES * 4);
    int2*  ed     = (int2*)take((size_t)N_NODES * CAP * 8);
    unsigned short* xb  = (unsigned short*)take((size_t)N_NODES * F_IN * 2);
    unsigned short* h2b = (unsigned short*)take((size_t)N_NODES * F_OUT * 2);
    unsigned short* W1t = (unsigned short*)take((size_t)F_IN * F_HID * 2);
    unsigned short* W2t = (unsigned short*)take((size_t)F_HID * F_OUT * 2);
    int*   mode   = (int*)take(4);

    int nF = (E + 1023) / 1024;
    pre_small_kernel<<<65, 256, 0, stream>>>(cur, (const unsigned*)ei, mode);
    prep_fill_kernel<<<nF + 2304, 256, 0, stream>>>(ei, mode, cur, ed, E, nF,
                                                    x, xb, W1, W1t, W2, W2t);
    // h0 = bf16( D^-1 (A+I) x ) stays in LDS; h2b = bf16( relu(LN(h0 W1 + b1)) W2 )
    agg_mlp_kernel<<<N_NODES / 16, 1024, 0, stream>>>(ew, cur, ed, invdeg,
                                                      (const unsigned*)xb, W1t, W2t,
                                                      b1, lng, lnb, h2b);
    // out = D^-1 (A+I) h2 + b2   (== (D^-1 (A+I) h) W2 + b2 by linearity)
    spmm2_kernel<<<N_NODES / 4, 256, 0, stream>>>((const unsigned*)h2b, cur, ed, invdeg,
                                                  b2, out);
}

// Round 7
// 195.001 us; speedup vs baseline: 1.0173x; 1.0173x over previous
//
#include <hip/hip_runtime.h>

#define N_NODES 16384
#define F_IN    128
#define F_HID   256
#define F_OUT   128
#define LN_EPS  1e-5f
#define CAP     128   // ELL slots/row; P(deg>128) ~ 1e-20 for Poisson(32)
#define H0STR   136   // LDS h0 stride (ushorts)
#define H1STR   264   // LDS post-LN stride (ushorts)
#define REPSTR  132   // LDS C2 repack stride (ushorts)
#define PLANEU  (N_NODES * 32)   // uints per 64-feature plane (128 B/node)

typedef __attribute__((ext_vector_type(8))) short bf16x8;
typedef __attribute__((ext_vector_type(4))) float f32x4;
typedef __attribute__((ext_vector_type(4))) int   i32x4;

__device__ __forceinline__ unsigned short bf16rne(float f) {
    unsigned u = __float_as_uint(f);
    unsigned r = (u + 0x7fffu + ((u >> 16) & 1u)) >> 16;   // round-to-nearest-even
    return (unsigned short)r;
}
__device__ __forceinline__ float bf_lo(unsigned v) { return __uint_as_float(v << 16); }
__device__ __forceinline__ float bf_hi(unsigned v) { return __uint_as_float(v & 0xffff0000u); }

// ---------------------------------------------------------------------------
// Tiny prologue: zero cur (blocks 0..63) + detect int64 vs int32 edge_index
// (block 64: odd u32 words all zero => int64).
__global__ void pre_small_kernel(int* __restrict__ cur, const unsigned* __restrict__ ei,
                                 int* __restrict__ mode) {
    int b = blockIdx.x, t = threadIdx.x;
    if (b < 64) {
        cur[b * 256 + t] = 0;
    } else {
        __shared__ int nz;
        if (t == 0) nz = 0;
        __syncthreads();
        for (int it = 0; it < 4; ++it) {
            int idx = 2 * (t + it * 256) + 1;
            if (ei[idx] != 0u) nz = 1;        // benign race
        }
        __syncthreads();
        if (t == 0) *mode = (nz == 0) ? 1 : 0;  // 1 => int64
    }
}

// ---------------------------------------------------------------------------
// Fused prep: ELL fill + x fp32->bf16 (PLANE layout: feats [0,64) then [64,128),
// 2.1 MB per plane so one plane fits an XCD L2 during the gather phase) +
// W1/W2 transpose-to-bf16, one grid.
__global__ void prep_fill_kernel(const void* __restrict__ ei, const int* __restrict__ mode,
                                 int* __restrict__ cur, int2* __restrict__ ed, int E, int nF,
                                 const float* __restrict__ x, unsigned short* __restrict__ xb,
                                 const float* __restrict__ W1, unsigned short* __restrict__ W1t,
                                 const float* __restrict__ W2, unsigned short* __restrict__ W2t) {
    int b = blockIdx.x, t = threadIdx.x;
    if (b < nF) {
        int base = b * 1024 + t;
        int m = *mode;
#pragma unroll
        for (int u = 0; u < 4; ++u) {
            int e = base + u * 256;
            if (e >= E) continue;
            int r, c;
            if (m) {
                const long long* p = (const long long*)ei;
                r = (int)p[e]; c = (int)p[e + E];
            } else {
                const int* p = (const int*)ei;
                r = p[e]; c = p[e + E];
            }
            if (((unsigned)r | (unsigned)c) >= N_NODES) continue;   // replay-safety guard
            int pos = atomicAdd(&cur[r], 1);
            if (pos < CAP) ed[r * CAP + pos] = make_int2(c, e);
        }
    } else if (b < nF + 2048) {
        int i = ((b - nF) * 256 + t) * 4;     // source feat-quad (row-major)
        float4 v = *(const float4*)&x[i];
        ushort4 o;
        o.x = bf16rne(v.x); o.y = bf16rne(v.y); o.z = bf16rne(v.z); o.w = bf16rne(v.w);
        int n = i >> 7, f = i & 127;
        int p = f >> 6, fo = f & 63;          // plane, offset-in-plane (mult of 4)
        *(ushort4*)&xb[(size_t)p * (N_NODES * 64) + n * 64 + fo] = o;
    } else if (b < nF + 2176) {
        int id = (b - nF - 2048) * 256 + t;   // [0, 32768)
        int n = id >> 7, k = id & 127;
        W1t[id] = bf16rne(W1[(size_t)k * F_HID + n]);
    } else {
        int id = (b - nF - 2176) * 256 + t;   // [0, 32768)
        int n = id >> 8, k = id & 255;
        W2t[id] = bf16rne(W2[(size_t)k * F_OUT + n]);
    }
}

// ---------------------------------------------------------------------------
// Fused dedupe + SpMM1 + MLP. 16 rows/block, 16 waves (1024 thr), 1 row/wave.
// Gather runs in TWO feature-plane phases (64 feats = 2.1 MB working set each,
// L2-resident per XCD) with a block barrier between -> round-5's 75 MB FETCH
// (xb 4.25 MB vs 4 MB L2 thrash) should halve. Dedupe is round-5's batched
// 16-wide compare (round-6 bitonic sort regressed: +11 us, 3.7M bank confl).
// Per-feature fp32 summation order unchanged -> bit-identical output.
__launch_bounds__(1024, 8)
__global__ void agg_mlp_kernel(const float* __restrict__ ew, int* __restrict__ cur,
                               int2* __restrict__ ed, float* __restrict__ invdeg,
                               const unsigned* __restrict__ xb,
                               const unsigned short* __restrict__ W1t,
                               const unsigned short* __restrict__ W2t,
                               const float* __restrict__ b1,
                               const float* __restrict__ ln_g, const float* __restrict__ ln_b,
                               unsigned short* __restrict__ h2b) {
    __shared__ int   scol[16][CAP];             // 8 KB
    __shared__ int   seid[16][CAP];             // 8 KB
    __shared__ float sw[16][CAP];               // 8 KB
    __shared__ unsigned short H0[16 * H0STR];   // 4.25 KB; reused as C2 repack
    __shared__ unsigned short H1[16 * H1STR];   // 8.25 KB
    __shared__ float red[2][16][16];            // 2 KB  (LN partial {s,q}[wave][row])

    int t = threadIdx.x, wave = t >> 6, lane = t & 63;
    int lnid = lane & 15, quad = lane >> 4;
    int half = lane >> 5, hl = lane & 31;
    int Rbase = blockIdx.x * 16;
    int r = Rbase + wave;

    // ---- stage {col, edge_id} of this wave's row into wave-private LDS ----
    int d = cur[r];
    if (d > CAP) d = CAP;
    int dpad = (d + 15) & ~15;
    int2* row = ed + (size_t)r * CAP;
    for (int i = lane; i < d; i += 64) {
        int2 e = row[i];
        scol[wave][i] = e.x;
        seid[wave][i] = e.y;
    }
    for (int i = d + lane; i < dpad; i += 64) {   // sentinel pad for 16-wide compare
        scol[wave][i] = -2;
        seid[wave][i] = 0;
    }
    asm volatile("s_waitcnt lgkmcnt(0)" ::: "memory");   // wave-local LDS ordering

    // ---- last-edge-wins dedupe + weight gather (batched 16-wide compares) ----
    float wsum = 0.0f;
    for (int i = lane; i < d; i += 64) {
        int myc = scol[wave][i], mye = seid[wave][i];
        bool kill = false;
        for (int jb = 0; jb < dpad; jb += 16) {
            const int* cb = &scol[wave][jb];
            const int* eb = &seid[wave][jb];
            i32x4 c0 = *(const i32x4*)(cb);
            i32x4 c1 = *(const i32x4*)(cb + 4);
            i32x4 c2 = *(const i32x4*)(cb + 8);
            i32x4 c3 = *(const i32x4*)(cb + 12);
            i32x4 e0 = *(const i32x4*)(eb);
            i32x4 e1 = *(const i32x4*)(eb + 4);
            i32x4 e2 = *(const i32x4*)(eb + 8);
            i32x4 e3 = *(const i32x4*)(eb + 12);
            kill |= (c0.x == myc && e0.x > mye);
            kill |= (c0.y == myc && e0.y > mye);
            kill |= (c0.z == myc && e0.z > mye);
            kill |= (c0.w == myc && e0.w > mye);
            kill |= (c1.x == myc && e1.x > mye);
            kill |= (c1.y == myc && e1.y > mye);
            kill |= (c1.z == myc && e1.z > mye);
            kill |= (c1.w == myc && e1.w > mye);
            kill |= (c2.x == myc && e2.x > mye);
            kill |= (c2.y == myc && e2.y > mye);
            kill |= (c2.z == myc && e2.z > mye);
            kill |= (c2.w == myc && e2.w > mye);
            kill |= (c3.x == myc && e3.x > mye);
            kill |= (c3.y == myc && e3.y > mye);
            kill |= (c3.z == myc && e3.z > mye);
            kill |= (c3.w == myc && e3.w > mye);
        }
        float w = kill ? 0.0f : ew[mye];
        sw[wave][i] = w;
        row[i] = make_int2(myc, __float_as_int(w));   // full 8B store (no RMW)
        wsum += w;
    }
    asm volatile("s_waitcnt lgkmcnt(0)" ::: "memory");
    for (int off = 32; off; off >>= 1) wsum += __shfl_xor(wsum, off, 64);
    float inv = 1.0f / (1.0f + wsum);                // +1 self-loop; >=1 so clip no-op
    if (lane == 0) { invdeg[r] = inv; cur[r] = d; }

    // ---- two-plane half-wave gather-SpMM: lane covers feats {2hl, 2hl+1} ----
    float selfw = half ? 0.0f : 1.0f;
#pragma unroll 1
    for (int p = 0; p < 2; ++p) {
        const unsigned* xp = xb + (size_t)p * PLANEU;
        unsigned sv = xp[r * 32 + hl];
        float a0 = selfw * bf_lo(sv), a1 = selfw * bf_hi(sv);
        int j = 0;
        for (; j + 16 <= d; j += 16) {
            int c[8]; float w[8]; unsigned v[8];
#pragma unroll
            for (int u = 0; u < 8; ++u) {
                c[u] = scol[wave][j + 2 * u + half];
                w[u] = sw[wave][j + 2 * u + half];
            }
#pragma unroll
            for (int u = 0; u < 8; ++u) v[u] = xp[c[u] * 32 + hl];
#pragma unroll
            for (int u = 0; u < 8; ++u) {
                a0 += w[u] * bf_lo(v[u]); a1 += w[u] * bf_hi(v[u]);
            }
        }
        for (; j + 2 <= d; j += 2) {
            int cc = scol[wave][j + half];
            float w = sw[wave][j + half];
            unsigned v = xp[cc * 32 + hl];
            a0 += w * bf_lo(v); a1 += w * bf_hi(v);
        }
        if (j < d) {                                  // odd tail: half 0 only
            int cc = scol[wave][j];
            float w = half ? 0.0f : sw[wave][j];
            unsigned v = xp[cc * 32 + hl];
            a0 += w * bf_lo(v); a1 += w * bf_hi(v);
        }
        a0 += __shfl_xor(a0, 32, 64);
        a1 += __shfl_xor(a1, 32, 64);
        if (half == 0) {
            unsigned w0 = ((unsigned)bf16rne(a1 * inv) << 16) | (unsigned)bf16rne(a0 * inv);
            *(unsigned*)&H0[wave * H0STR + p * 64 + hl * 2] = w0;   // 4B aligned
        }
        __syncthreads();   // phase-align all 16 waves per plane (+ H0 ordering)
    }

    // ---- stage A: C1[16x256] = h0 @ W1, K=128; wave handles ct = wave ----
    bf16x8 a[4];
#pragma unroll
    for (int ch = 0; ch < 4; ++ch)
        a[ch] = *(const bf16x8*)&H0[lnid * H0STR + ch * 32 + quad * 8];
    f32x4 acc = {0.0f, 0.0f, 0.0f, 0.0f};
    {
        const unsigned short* wrow = &W1t[(size_t)(wave * 16 + lnid) * F_IN];
#pragma unroll
        for (int ch = 0; ch < 4; ++ch) {
            bf16x8 b = *(const bf16x8*)&wrow[ch * 32 + quad * 8];
            acc = __builtin_amdgcn_mfma_f32_16x16x32_bf16(a[ch], b, acc, 0, 0, 0);
        }
    }
    // bias + LN partial stats (rows in (quad,reg); this wave's 16 cols in lnid)
    float s[4], q[4];
    {
        float bv = b1[wave * 16 + lnid];
#pragma unroll
        for (int rr = 0; rr < 4; ++rr) {
            float v = acc[rr] + bv;
            acc[rr] = v;
            s[rr] = v; q[rr] = v * v;
        }
    }
#pragma unroll
    for (int rr = 0; rr < 4; ++rr)
        for (int off = 1; off < 16; off <<= 1) {
            s[rr] += __shfl_xor(s[rr], off, 64);
            q[rr] += __shfl_xor(q[rr], off, 64);
        }
    if (lnid == 0) {
#pragma unroll
        for (int rr = 0; rr < 4; ++rr) {
            red[0][wave][quad * 4 + rr] = s[rr];
            red[1][wave][quad * 4 + rr] = q[rr];
        }
    }
    __syncthreads();
    float mean[4], rinv[4];
#pragma unroll
    for (int rr = 0; rr < 4; ++rr) {
        int rowi = quad * 4 + rr;
        float S = 0.0f, Q = 0.0f;
#pragma unroll
        for (int w2 = 0; w2 < 16; ++w2) { S += red[0][w2][rowi]; Q += red[1][w2][rowi]; }
        mean[rr] = S * (1.0f / F_HID);
        float var = Q * (1.0f / F_HID) - mean[rr] * mean[rr];
        rinv[rr] = rsqrtf(var + LN_EPS);
    }
    {
        int c = wave * 16 + lnid;
        float g = ln_g[c], bb = ln_b[c];
#pragma unroll
        for (int rr = 0; rr < 4; ++rr) {
            float v = fmaxf((acc[rr] - mean[rr]) * rinv[rr] * g + bb, 0.0f);
            H1[(quad * 4 + rr) * H1STR + c] = bf16rne(v);
        }
    }
    __syncthreads();   // H1 complete; H0 a-frags long consumed -> reusable

    // ---- stage B: C2[16x128] = H1 @ W2, K=256; waves 0-7, ct = wave ----
    unsigned short* rep = H0;   // repack area (16 x REPSTR fits in 16 x H0STR)
    if (wave < 8) {
        bf16x8 a2[8];
#pragma unroll
        for (int ch = 0; ch < 8; ++ch)
            a2[ch] = *(const bf16x8*)&H1[lnid * H1STR + ch * 32 + quad * 8];
        f32x4 c2 = {0.0f, 0.0f, 0.0f, 0.0f};
        const unsigned short* wrow = &W2t[(size_t)(wave * 16 + lnid) * F_HID];
#pragma unroll
        for (int ch = 0; ch < 8; ++ch) {
            bf16x8 b = *(const bf16x8*)&wrow[ch * 32 + quad * 8];
            c2 = __builtin_amdgcn_mfma_f32_16x16x32_bf16(a2[ch], b, c2, 0, 0, 0);
        }
#pragma unroll
        for (int rr = 0; rr < 4; ++rr)
            rep[(quad * 4 + rr) * REPSTR + wave * 16 + lnid] = bf16rne(c2[rr]);
    }
    __syncthreads();   // drain before coalesced readback

    // plane-layout store: 16 rows x 128 bf16 (512 ushort4, threads 0..511)
    if (t < 512) {
        int m = t >> 5, cg = t & 31;
        int p = cg >> 4, fo = (cg & 15) * 4;
        *(ushort4*)&h2b[(size_t)p * (N_NODES * 64) + (size_t)(Rbase + m) * 64 + fo] =
            *(const ushort4*)&rep[m * REPSTR + cg * 4];
    }
}

// ---------------------------------------------------------------------------
// Gather SpMM (ELL, deduped weights in ed.y, PLANE layout source): 16 waves /
// block, 1 row/wave, row staged in LDS, two plane phases with block barrier
// (same L2-residency argument as agg). Epilogue: out = acc*invdeg + bias.
__launch_bounds__(1024, 8)
__global__ void spmm2_kernel(const unsigned* __restrict__ xb, const int* __restrict__ cur,
                             const int2* __restrict__ ed, const float* __restrict__ invdeg,
                             const float* __restrict__ bias, float* __restrict__ outp) {
    __shared__ int   scol[16][CAP];             // 8 KB
    __shared__ float sw[16][CAP];               // 8 KB
    int t = threadIdx.x, wave = t >> 6, lane = t & 63;
    int half = lane >> 5, hl = lane & 31;
    int r = blockIdx.x * 16 + wave;
    const int2* row = ed + (size_t)r * CAP;
    int d = cur[r];
    if (d > CAP) d = CAP;
    for (int i = lane; i < d; i += 64) {
        int2 e = row[i];
        scol[wave][i] = e.x;
        sw[wave][i] = __int_as_float(e.y);
    }
    asm volatile("s_waitcnt lgkmcnt(0)" ::: "memory");   // wave-local LDS ordering

    float inv = invdeg[r];
    float selfw = half ? 0.0f : 1.0f;
#pragma unroll 1
    for (int p = 0; p < 2; ++p) {
        const unsigned* xp = xb + (size_t)p * PLANEU;
        unsigned sv = xp[r * 32 + hl];
        float a0 = selfw * bf_lo(sv), a1 = selfw * bf_hi(sv);
        int j = 0;
        for (; j + 16 <= d; j += 16) {
            int c[8]; float w[8]; unsigned v[8];
#pragma unroll
            for (int u = 0; u < 8; ++u) {
                c[u] = scol[wave][j + 2 * u + half];
                w[u] = sw[wave][j + 2 * u + half];
            }
#pragma unroll
            for (int u = 0; u < 8; ++u) v[u] = xp[c[u] * 32 + hl];
#pragma unroll
            for (int u = 0; u < 8; ++u) {
                a0 += w[u] * bf_lo(v[u]); a1 += w[u] * bf_hi(v[u]);
            }
        }
        for (; j + 2 <= d; j += 2) {
            int cc = scol[wave][j + half];
            float w = sw[wave][j + half];
            unsigned v = xp[cc * 32 + hl];
            a0 += w * bf_lo(v); a1 += w * bf_hi(v);
        }
        if (j < d) {                                  // odd tail: half 0 only
            int cc = scol[wave][j];
            float w = half ? 0.0f : sw[wave][j];
            unsigned v = xp[cc * 32 + hl];
            a0 += w * bf_lo(v); a1 += w * bf_hi(v);
        }
        a0 += __shfl_xor(a0, 32, 64);
        a1 += __shfl_xor(a1, 32, 64);
        if (half == 0) {
            int f = p * 64 + 2 * hl;
            float2 o;
            o.x = a0 * inv + bias[f];
            o.y = a1 * inv + bias[f + 1];
            *(float2*)&outp[(size_t)r * F_OUT + f] = o;
        }
        __syncthreads();   // phase-align all 16 waves per plane
    }
}

// ---------------------------------------------------------------------------
extern "C" void kernel_launch(void* const* d_in, const int* in_sizes, int n_in,
                              void* d_out, int out_size, void* d_ws, size_t ws_size,
                              hipStream_t stream) {
    const float* x   = (const float*)d_in[0];
    const void*  ei  = d_in[1];
    const float* ew  = (const float*)d_in[2];
    const float* W1  = (const float*)d_in[3];
    const float* b1  = (const float*)d_in[4];
    const float* W2  = (const float*)d_in[5];
    const float* b2  = (const float*)d_in[6];
    const float* lng = (const float*)d_in[7];
    const float* lnb = (const float*)d_in[8];
    float* out = (float*)d_out;
    int E = in_sizes[2];

    char* w = (char*)d_ws;
    size_t off = 0;
    auto take = [&](size_t bytes) -> char* {
        char* p = w + off;
        off += (bytes + 255) & ~(size_t)255;
        return p;
    };
    int*   cur    = (int*)take((size_t)N_NODES * 4);
    float* invdeg = (float*)take((size_t)N_NODES * 4);
    int2*  ed     = (int2*)take((size_t)N_NODES * CAP * 8);
    unsigned short* xb  = (unsigned short*)take((size_t)N_NODES * F_IN * 2);
    unsigned short* h2b = (unsigned short*)take((size_t)N_NODES * F_OUT * 2);
    unsigned short* W1t = (unsigned short*)take((size_t)F_IN * F_HID * 2);
    unsigned short* W2t = (unsigned short*)take((size_t)F_HID * F_OUT * 2);
    int*   mode   = (int*)take(4);

    int nF = (E + 1023) / 1024;
    pre_small_kernel<<<65, 256, 0, stream>>>(cur, (const unsigned*)ei, mode);
    prep_fill_kernel<<<nF + 2304, 256, 0, stream>>>(ei, mode, cur, ed, E, nF,
                                                    x, xb, W1, W1t, W2, W2t);
    // h0 = bf16( D^-1 (A+I) x ) stays in LDS; h2b = bf16( relu(LN(h0 W1 + b1)) W2 )
    agg_mlp_kernel<<<N_NODES / 16, 1024, 0, stream>>>(ew, cur, ed, invdeg,
                                                      (const unsigned*)xb, W1t, W2t,
                                                      b1, lng, lnb, h2b);
    // out = D^-1 (A+I) h2 + b2   (== (D^-1 (A+I) h) W2 + b2 by linearity)
    spmm2_kernel<<<N_NODES / 16, 1024, 0, stream>>>((const unsigned*)h2b, cur, ed, invdeg,
                                                    b2, out);
}

// Round 8
// 182.276 us; speedup vs baseline: 1.0883x; 1.0698x over previous
//
#include <hip/hip_runtime.h>

#define N_NODES 16384
#define F_IN    128
#define F_HID   256
#define F_OUT   128
#define LN_EPS  1e-5f
#define CAP     128   // ELL slots/row; P(deg>128) ~ 1e-20 for Poisson(32)
#define H0STR   136   // LDS h0 stride (ushorts); 272 B = 17x16 -> 16B-aligned rows
#define H1STR   264   // LDS post-LN stride (ushorts)
#define REPSTR  132   // LDS C2 repack stride (ushorts)

typedef __attribute__((ext_vector_type(8))) short bf16x8;
typedef __attribute__((ext_vector_type(4))) float f32x4;
typedef __attribute__((ext_vector_type(4))) int   i32x4;
typedef __attribute__((ext_vector_type(4))) unsigned u32x4;

__device__ __forceinline__ unsigned short bf16rne(float f) {
    unsigned u = __float_as_uint(f);
    unsigned r = (u + 0x7fffu + ((u >> 16) & 1u)) >> 16;   // round-to-nearest-even
    return (unsigned short)r;
}
__device__ __forceinline__ float bf_lo(unsigned v) { return __uint_as_float(v << 16); }
__device__ __forceinline__ float bf_hi(unsigned v) { return __uint_as_float(v & 0xffff0000u); }

// ---------------------------------------------------------------------------
// Tiny prologue: zero cur (blocks 0..63) + detect int64 vs int32 edge_index
// (block 64: odd u32 words all zero => int64).
__global__ void pre_small_kernel(int* __restrict__ cur, const unsigned* __restrict__ ei,
                                 int* __restrict__ mode) {
    int b = blockIdx.x, t = threadIdx.x;
    if (b < 64) {
        cur[b * 256 + t] = 0;
    } else {
        __shared__ int nz;
        if (t == 0) nz = 0;
        __syncthreads();
        for (int it = 0; it < 4; ++it) {
            int idx = 2 * (t + it * 256) + 1;
            if (ei[idx] != 0u) nz = 1;        // benign race
        }
        __syncthreads();
        if (t == 0) *mode = (nz == 0) ? 1 : 0;  // 1 => int64
    }
}

// ---------------------------------------------------------------------------
// Fused prep: ELL fill + x fp32->bf16 (row-major) + W1/W2 transpose-to-bf16.
__global__ void prep_fill_kernel(const void* __restrict__ ei, const int* __restrict__ mode,
                                 int* __restrict__ cur, int2* __restrict__ ed, int E, int nF,
                                 const float* __restrict__ x, unsigned short* __restrict__ xb,
                                 const float* __restrict__ W1, unsigned short* __restrict__ W1t,
                                 const float* __restrict__ W2, unsigned short* __restrict__ W2t) {
    int b = blockIdx.x, t = threadIdx.x;
    if (b < nF) {
        int base = b * 1024 + t;
        int m = *mode;
#pragma unroll
        for (int u = 0; u < 4; ++u) {
            int e = base + u * 256;
            if (e >= E) continue;
            int r, c;
            if (m) {
                const long long* p = (const long long*)ei;
                r = (int)p[e]; c = (int)p[e + E];
            } else {
                const int* p = (const int*)ei;
                r = p[e]; c = p[e + E];
            }
            if (((unsigned)r | (unsigned)c) >= N_NODES) continue;   // replay-safety guard
            int pos = atomicAdd(&cur[r], 1);
            if (pos < CAP) ed[r * CAP + pos] = make_int2(c, e);
        }
    } else if (b < nF + 2048) {
        int i = ((b - nF) * 256 + t) * 4;
        float4 v = *(const float4*)&x[i];
        ushort4 o;
        o.x = bf16rne(v.x); o.y = bf16rne(v.y); o.z = bf16rne(v.z); o.w = bf16rne(v.w);
        *(ushort4*)&xb[i] = o;
    } else if (b < nF + 2176) {
        int id = (b - nF - 2048) * 256 + t;   // [0, 32768)
        int n = id >> 7, k = id & 127;
        W1t[id] = bf16rne(W1[(size_t)k * F_HID + n]);
    } else {
        int id = (b - nF - 2176) * 256 + t;   // [0, 32768)
        int n = id >> 8, k = id & 255;
        W2t[id] = bf16rne(W2[(size_t)k * F_OUT + n]);
    }
}

// ---------------------------------------------------------------------------
// Quarter-wave gather core: qw = lane>>4 (quarter id), ql = lane&15.
// One uint4 load = 16 B = 8 bf16 feats [ql*8, ql*8+8) of ONE neighbor; the 4
// quarters cover 4 neighbors per load slot -> half the load instructions and
// half the LDS broadcast reads of the uint2 scheme (round-5). Quarters are
// combined at the end with shfl_xor(16) + shfl_xor(32).
// ---------------------------------------------------------------------------
// Fused dedupe + SpMM1 + MLP. 16 rows/block, 16 waves (1024 thr), 1 row/wave.
// Dedupe is round-5's batched 16-wide compare (bit-identical kill rule).
__launch_bounds__(1024, 8)
__global__ void agg_mlp_kernel(const float* __restrict__ ew, int* __restrict__ cur,
                               int2* __restrict__ ed, float* __restrict__ invdeg,
                               const unsigned* __restrict__ xb,
                               const unsigned short* __restrict__ W1t,
                               const unsigned short* __restrict__ W2t,
                               const float* __restrict__ b1,
                               const float* __restrict__ ln_g, const float* __restrict__ ln_b,
                               unsigned short* __restrict__ h2b) {
    __shared__ int   scol[16][CAP];             // 8 KB
    __shared__ int   seid[16][CAP];             // 8 KB
    __shared__ float sw[16][CAP];               // 8 KB
    __shared__ unsigned short H0[16 * H0STR];   // 4.25 KB; reused as C2 repack
    __shared__ unsigned short H1[16 * H1STR];   // 8.25 KB
    __shared__ float red[2][16][16];            // 2 KB  (LN partial {s,q}[wave][row])

    int t = threadIdx.x, wave = t >> 6, lane = t & 63;
    int lnid = lane & 15, quad = lane >> 4;
    int qw = lane >> 4, ql = lane & 15;         // quarter id / lane-in-quarter
    int Rbase = blockIdx.x * 16;
    int r = Rbase + wave;

    // ---- stage {col, edge_id} of this wave's row into wave-private LDS ----
    int d = cur[r];
    if (d > CAP) d = CAP;
    int dpad = (d + 15) & ~15;
    int2* row = ed + (size_t)r * CAP;
    for (int i = lane; i < d; i += 64) {
        int2 e = row[i];
        scol[wave][i] = e.x;
        seid[wave][i] = e.y;
    }
    for (int i = d + lane; i < dpad; i += 64) {   // sentinel pad for 16-wide compare
        scol[wave][i] = -2;
        seid[wave][i] = 0;
    }
    asm volatile("s_waitcnt lgkmcnt(0)" ::: "memory");   // wave-local LDS ordering

    // ---- last-edge-wins dedupe + weight gather (batched 16-wide compares) ----
    float wsum = 0.0f;
    for (int i = lane; i < d; i += 64) {
        int myc = scol[wave][i], mye = seid[wave][i];
        bool kill = false;
        for (int jb = 0; jb < dpad; jb += 16) {
            const int* cb = &scol[wave][jb];
            const int* eb = &seid[wave][jb];
            i32x4 c0 = *(const i32x4*)(cb);
            i32x4 c1 = *(const i32x4*)(cb + 4);
            i32x4 c2 = *(const i32x4*)(cb + 8);
            i32x4 c3 = *(const i32x4*)(cb + 12);
            i32x4 e0 = *(const i32x4*)(eb);
            i32x4 e1 = *(const i32x4*)(eb + 4);
            i32x4 e2 = *(const i32x4*)(eb + 8);
            i32x4 e3 = *(const i32x4*)(eb + 12);
            kill |= (c0.x == myc && e0.x > mye);
            kill |= (c0.y == myc && e0.y > mye);
            kill |= (c0.z == myc && e0.z > mye);
            kill |= (c0.w == myc && e0.w > mye);
            kill |= (c1.x == myc && e1.x > mye);
            kill |= (c1.y == myc && e1.y > mye);
            kill |= (c1.z == myc && e1.z > mye);
            kill |= (c1.w == myc && e1.w > mye);
            kill |= (c2.x == myc && e2.x > mye);
            kill |= (c2.y == myc && e2.y > mye);
            kill |= (c2.z == myc && e2.z > mye);
            kill |= (c2.w == myc && e2.w > mye);
            kill |= (c3.x == myc && e3.x > mye);
            kill |= (c3.y == myc && e3.y > mye);
            kill |= (c3.z == myc && e3.z > mye);
            kill |= (c3.w == myc && e3.w > mye);
        }
        float w = kill ? 0.0f : ew[mye];
        sw[wave][i] = w;
        row[i] = make_int2(myc, __float_as_int(w));   // full 8B store (no RMW)
        wsum += w;
    }
    asm volatile("s_waitcnt lgkmcnt(0)" ::: "memory");
    for (int off = 32; off; off >>= 1) wsum += __shfl_xor(wsum, off, 64);
    float inv = 1.0f / (1.0f + wsum);                // +1 self-loop; >=1 so clip no-op
    if (lane == 0) { invdeg[r] = inv; cur[r] = d; }

    // ---- quarter-wave uint4 gather-SpMM: lane covers feats [ql*8, ql*8+8) ----
    const u32x4* xb4 = (const u32x4*)xb;             // 16 B units; node row = 16 units
    float a[8] = {0, 0, 0, 0, 0, 0, 0, 0};
    int j = 0;
    for (; j + 16 <= d; j += 16) {                   // 16 neighbors / 4 loads in flight
        int c[4]; float w[4]; u32x4 v[4];
#pragma unroll
        for (int u = 0; u < 4; ++u) {
            int n = j + u * 4 + qw;
            c[u] = scol[wave][n];
            w[u] = sw[wave][n];
        }
#pragma unroll
        for (int u = 0; u < 4; ++u) v[u] = xb4[(size_t)c[u] * 16 + ql];
#pragma unroll
        for (int u = 0; u < 4; ++u)
#pragma unroll
            for (int m = 0; m < 4; ++m) {
                a[2 * m]     += w[u] * bf_lo(v[u][m]);
                a[2 * m + 1] += w[u] * bf_hi(v[u][m]);
            }
    }
    for (; j + 4 <= d; j += 4) {                     // 4-neighbor tail
        int n = j + qw;
        int c = scol[wave][n];
        float w = sw[wave][n];
        u32x4 v = xb4[(size_t)c * 16 + ql];
#pragma unroll
        for (int m = 0; m < 4; ++m) {
            a[2 * m]     += w * bf_lo(v[m]);
            a[2 * m + 1] += w * bf_hi(v[m]);
        }
    }
    int rem = d - j;
    if (rem > 0) {                                   // <4 tail: idle quarters w=0
        int n = j + (qw < rem ? qw : 0);
        float w = (qw < rem) ? sw[wave][n] : 0.0f;
        int c = scol[wave][n];
        u32x4 v = xb4[(size_t)c * 16 + ql];
#pragma unroll
        for (int m = 0; m < 4; ++m) {
            a[2 * m]     += w * bf_lo(v[m]);
            a[2 * m + 1] += w * bf_hi(v[m]);
        }
    }
#pragma unroll
    for (int k = 0; k < 8; ++k) {                    // combine the 4 quarters
        a[k] += __shfl_xor(a[k], 16, 64);
        a[k] += __shfl_xor(a[k], 32, 64);
    }
    if (qw == 0) {                                   // + self, scale, bf16, H0 write
        u32x4 sv = xb4[(size_t)r * 16 + ql];
        u32x4 o;
#pragma unroll
        for (int m = 0; m < 4; ++m) {
            float lo = (a[2 * m]     + bf_lo(sv[m])) * inv;
            float hi = (a[2 * m + 1] + bf_hi(sv[m])) * inv;
            o[m] = ((unsigned)bf16rne(hi) << 16) | (unsigned)bf16rne(lo);
        }
        *(u32x4*)&H0[wave * H0STR + ql * 8] = o;     // 16 B aligned (H0STR=136)
    }
    __syncthreads();   // all 16 h0 rows staged

    // ---- stage A: C1[16x256] = h0 @ W1, K=128; wave handles ct = wave ----
    bf16x8 afr[4];
#pragma unroll
    for (int ch = 0; ch < 4; ++ch)
        afr[ch] = *(const bf16x8*)&H0[lnid * H0STR + ch * 32 + quad * 8];
    f32x4 acc = {0.0f, 0.0f, 0.0f, 0.0f};
    {
        const unsigned short* wrow = &W1t[(size_t)(wave * 16 + lnid) * F_IN];
#pragma unroll
        for (int ch = 0; ch < 4; ++ch) {
            bf16x8 b = *(const bf16x8*)&wrow[ch * 32 + quad * 8];
            acc = __builtin_amdgcn_mfma_f32_16x16x32_bf16(afr[ch], b, acc, 0, 0, 0);
        }
    }
    // bias + LN partial stats (rows in (quad,reg); this wave's 16 cols in lnid)
    float s[4], q[4];
    {
        float bv = b1[wave * 16 + lnid];
#pragma unroll
        for (int rr = 0; rr < 4; ++rr) {
            float v = acc[rr] + bv;
            acc[rr] = v;
            s[rr] = v; q[rr] = v * v;
        }
    }
#pragma unroll
    for (int rr = 0; rr < 4; ++rr)
        for (int off = 1; off < 16; off <<= 1) {
            s[rr] += __shfl_xor(s[rr], off, 64);
            q[rr] += __shfl_xor(q[rr], off, 64);
        }
    if (lnid == 0) {
#pragma unroll
        for (int rr = 0; rr < 4; ++rr) {
            red[0][wave][quad * 4 + rr] = s[rr];
            red[1][wave][quad * 4 + rr] = q[rr];
        }
    }
    __syncthreads();
    float mean[4], rinv[4];
#pragma unroll
    for (int rr = 0; rr < 4; ++rr) {
        int rowi = quad * 4 + rr;
        float S = 0.0f, Q = 0.0f;
#pragma unroll
        for (int w2 = 0; w2 < 16; ++w2) { S += red[0][w2][rowi]; Q += red[1][w2][rowi]; }
        mean[rr] = S * (1.0f / F_HID);
        float var = Q * (1.0f / F_HID) - mean[rr] * mean[rr];
        rinv[rr] = rsqrtf(var + LN_EPS);
    }
    {
        int c = wave * 16 + lnid;
        float g = ln_g[c], bb = ln_b[c];
#pragma unroll
        for (int rr = 0; rr < 4; ++rr) {
            float v = fmaxf((acc[rr] - mean[rr]) * rinv[rr] * g + bb, 0.0f);
            H1[(quad * 4 + rr) * H1STR + c] = bf16rne(v);
        }
    }
    __syncthreads();   // H1 complete; H0 a-frags long consumed -> reusable

    // ---- stage B: C2[16x128] = H1 @ W2, K=256; waves 0-7, ct = wave ----
    unsigned short* rep = H0;   // repack area (16 x REPSTR fits in 16 x H0STR)
    if (wave < 8) {
        bf16x8 a2[8];
#pragma unroll
        for (int ch = 0; ch < 8; ++ch)
            a2[ch] = *(const bf16x8*)&H1[lnid * H1STR + ch * 32 + quad * 8];
        f32x4 c2 = {0.0f, 0.0f, 0.0f, 0.0f};
        const unsigned short* wrow = &W2t[(size_t)(wave * 16 + lnid) * F_HID];
#pragma unroll
        for (int ch = 0; ch < 8; ++ch) {
            bf16x8 b = *(const bf16x8*)&wrow[ch * 32 + quad * 8];
            c2 = __builtin_amdgcn_mfma_f32_16x16x32_bf16(a2[ch], b, c2, 0, 0, 0);
        }
#pragma unroll
        for (int rr = 0; rr < 4; ++rr)
            rep[(quad * 4 + rr) * REPSTR + wave * 16 + lnid] = bf16rne(c2[rr]);
    }
    __syncthreads();   // drain before coalesced readback

    // coalesced store: 16 rows x 128 bf16 (512 ushort4, threads 0..511)
    if (t < 512) {
        int m = t >> 5, cg = t & 31;
        *(ushort4*)&h2b[(size_t)(Rbase + m) * F_OUT + cg * 4] =
            *(const ushort4*)&rep[m * REPSTR + cg * 4];
    }
}

// ---------------------------------------------------------------------------
// Gather SpMM (ELL, deduped weights in ed.y): 16 waves/block, 1 row/wave,
// row staged in LDS, quarter-wave uint4 gathers. out = acc*invdeg + bias.
__launch_bounds__(1024, 8)
__global__ void spmm2_kernel(const unsigned* __restrict__ xb, const int* __restrict__ cur,
                             const int2* __restrict__ ed, const float* __restrict__ invdeg,
                             const float* __restrict__ bias, float* __restrict__ outp) {
    __shared__ int   scol[16][CAP];             // 8 KB
    __shared__ float sw[16][CAP];               // 8 KB
    int t = threadIdx.x, wave = t >> 6, lane = t & 63;
    int qw = lane >> 4, ql = lane & 15;
    int r = blockIdx.x * 16 + wave;
    const int2* row = ed + (size_t)r * CAP;
    int d = cur[r];
    if (d > CAP) d = CAP;
    for (int i = lane; i < d; i += 64) {
        int2 e = row[i];
        scol[wave][i] = e.x;
        sw[wave][i] = __int_as_float(e.y);
    }
    asm volatile("s_waitcnt lgkmcnt(0)" ::: "memory");   // wave-local LDS ordering

    const u32x4* xb4 = (const u32x4*)xb;
    float a[8] = {0, 0, 0, 0, 0, 0, 0, 0};
    int j = 0;
    for (; j + 16 <= d; j += 16) {
        int c[4]; float w[4]; u32x4 v[4];
#pragma unroll
        for (int u = 0; u < 4; ++u) {
            int n = j + u * 4 + qw;
            c[u] = scol[wave][n];
            w[u] = sw[wave][n];
        }
#pragma unroll
        for (int u = 0; u < 4; ++u) v[u] = xb4[(size_t)c[u] * 16 + ql];
#pragma unroll
        for (int u = 0; u < 4; ++u)
#pragma unroll
            for (int m = 0; m < 4; ++m) {
                a[2 * m]     += w[u] * bf_lo(v[u][m]);
                a[2 * m + 1] += w[u] * bf_hi(v[u][m]);
            }
    }
    for (; j + 4 <= d; j += 4) {
        int n = j + qw;
        int c = scol[wave][n];
        float w = sw[wave][n];
        u32x4 v = xb4[(size_t)c * 16 + ql];
#pragma unroll
        for (int m = 0; m < 4; ++m) {
            a[2 * m]     += w * bf_lo(v[m]);
            a[2 * m + 1] += w * bf_hi(v[m]);
        }
    }
    int rem = d - j;
    if (rem > 0) {
        int n = j + (qw < rem ? qw : 0);
        float w = (qw < rem) ? sw[wave][n] : 0.0f;
        int c = scol[wave][n];
        u32x4 v = xb4[(size_t)c * 16 + ql];
#pragma unroll
        for (int m = 0; m < 4; ++m) {
            a[2 * m]     += w * bf_lo(v[m]);
            a[2 * m + 1] += w * bf_hi(v[m]);
        }
    }
#pragma unroll
    for (int k = 0; k < 8; ++k) {
        a[k] += __shfl_xor(a[k], 16, 64);
        a[k] += __shfl_xor(a[k], 32, 64);
    }
    if (qw == 0) {                                   // + self, scale, bias, store
        float inv = invdeg[r];
        u32x4 sv = xb4[(size_t)r * 16 + ql];
        int f = ql * 8;
        f32x4 o0, o1;
#pragma unroll
        for (int m = 0; m < 2; ++m) {
            o0[2 * m]     = (a[2 * m]     + bf_lo(sv[m])) * inv + bias[f + 2 * m];
            o0[2 * m + 1] = (a[2 * m + 1] + bf_hi(sv[m])) * inv + bias[f + 2 * m + 1];
        }
#pragma unroll
        for (int m = 2; m < 4; ++m) {
            o1[2 * m - 4] = (a[2 * m]     + bf_lo(sv[m])) * inv + bias[f + 2 * m];
            o1[2 * m - 3] = (a[2 * m + 1] + bf_hi(sv[m])) * inv + bias[f + 2 * m + 1];
        }
        *(f32x4*)&outp[(size_t)r * F_OUT + f]     = o0;
        *(f32x4*)&outp[(size_t)r * F_OUT + f + 4] = o1;
    }
}

// ---------------------------------------------------------------------------
extern "C" void kernel_launch(void* const* d_in, const int* in_sizes, int n_in,
                              void* d_out, int out_size, void* d_ws, size_t ws_size,
                              hipStream_t stream) {
    const float* x   = (const float*)d_in[0];
    const void*  ei  = d_in[1];
    const float* ew  = (const float*)d_in[2];
    const float* W1  = (const float*)d_in[3];
    const float* b1  = (const float*)d_in[4];
    const float* W2  = (const float*)d_in[5];
    const float* b2  = (const float*)d_in[6];
    const float* lng = (const float*)d_in[7];
    const float* lnb = (const float*)d_in[8];
    float* out = (float*)d_out;
    int E = in_sizes[2];

    char* w = (char*)d_ws;
    size_t off = 0;
    auto take = [&](size_t bytes) -> char* {
        char* p = w + off;
        off += (bytes + 255) & ~(size_t)255;
        return p;
    };
    int*   cur    = (int*)take((size_t)N_NODES * 4);
    float* invdeg = (float*)take((size_t)N_NODES * 4);
    int2*  ed     = (int2*)take((size_t)N_NODES * CAP * 8);
    unsigned short* xb  = (unsigned short*)take((size_t)N_NODES * F_IN * 2);
    unsigned short* h2b = (unsigned short*)take((size_t)N_NODES * F_OUT * 2);
    unsigned short* W1t = (unsigned short*)take((size_t)F_IN * F_HID * 2);
    unsigned short* W2t = (unsigned short*)take((size_t)F_HID * F_OUT * 2);
    int*   mode   = (int*)take(4);

    int nF = (E + 1023) / 1024;
    pre_small_kernel<<<65, 256, 0, stream>>>(cur, (const unsigned*)ei, mode);
    prep_fill_kernel<<<nF + 2304, 256, 0, stream>>>(ei, mode, cur, ed, E, nF,
                                                    x, xb, W1, W1t, W2, W2t);
    // h0 = bf16( D^-1 (A+I) x ) stays in LDS; h2b = bf16( relu(LN(h0 W1 + b1)) W2 )
    agg_mlp_kernel<<<N_NODES / 16, 1024, 0, stream>>>(ew, cur, ed, invdeg,
                                                      (const unsigned*)xb, W1t, W2t,
                                                      b1, lng, lnb, h2b);
    // out = D^-1 (A+I) h2 + b2   (== (D^-1 (A+I) h) W2 + b2 by linearity)
    spmm2_kernel<<<N_NODES / 16, 1024, 0, stream>>>((const unsigned*)h2b, cur, ed, invdeg,
                                                    b2, out);
}